// Round 19
// baseline (119.852 us; speedup 1.0000x reference)
//
#include <hip/hip_runtime.h>
#include <math.h>

#define PI_F 3.14159265358979323846f

typedef float v2f __attribute__((ext_vector_type(2)));
typedef float f4 __attribute__((ext_vector_type(4)));
typedef _Float16 h2 __attribute__((ext_vector_type(2)));
typedef _Float16 h8 __attribute__((ext_vector_type(8)));

// ---------------------------------------------------------------------------
// R18 = R17 (MFMA passes) + ping-pong double-buffered LDS (1 barrier/pass)
// + pkrtz packing.
// Pass ps reads buf[ps&1], writes buf[(ps+1)&1]: the mid-pass barrier that
// guarded the single-buffer WAR hazard is gone. Readout reads buf[1]
// (pass 14 writes it; final layout = identity).
// All GF(2) layout machinery identical to R17.
// ---------------------------------------------------------------------------
struct Tab {
    int      ggate[15][4];           // gate index (layer*12 + wire)
    unsigned smask[15][4];           // {L(m0), L(m3), L(nb4)=ct0, L(nb5)=ct1}
    unsigned short qstore[15][256];  // store base (a0=0,a3=0,ct=0) per thread
    unsigned short init_t[256];      // L_0(t)
    unsigned short initk[16];        // L_0(k<<8)
    unsigned zrow[12];               // final measurement parity rows
};

constexpr int nullspace12(const unsigned* rows, int nr, unsigned* out) {
    unsigned R[8] = {};
    for (int i = 0; i < nr; ++i) R[i] = rows[i];
    int pivc[8] = {};
    int rank = 0;
    for (int c = 11; c >= 0; --c) {
        int sel = -1;
        for (int i = rank; i < nr; ++i) if ((R[i] >> c) & 1u) { sel = i; break; }
        if (sel < 0) continue;
        unsigned tmp = R[rank]; R[rank] = R[sel]; R[sel] = tmp;
        for (int i = 0; i < nr; ++i)
            if (i != rank && ((R[i] >> c) & 1u)) R[i] ^= R[rank];
        pivc[rank] = c; ++rank;
    }
    int nn = 0;
    for (int c = 0; c < 12; ++c) {
        bool isp = false;
        for (int i = 0; i < rank; ++i) if (pivc[i] == c) isp = true;
        if (isp) continue;
        unsigned v = 1u << c;
        for (int i = 0; i < rank; ++i)
            if ((R[i] >> c) & 1u) v |= 1u << pivc[i];
        out[nn++] = v;
    }
    return nn;
}

struct LMap {
    unsigned eb[12];
    unsigned ei[12];
    unsigned lb[12];
    int n;
};

constexpr unsigned lead_bit(unsigned v) {
    unsigned lb = 0;
    for (int c = 11; c >= 0; --c) if ((v >> c) & 1u) { lb = 1u << c; break; }
    return lb;
}

constexpr LMap build_lmap(const unsigned* B, const unsigned* I) {
    LMap m{};
    m.n = 0;
    for (int i = 0; i < 12; ++i) {
        unsigned v = B[i], im = I[i];
        for (int j = 0; j < m.n; ++j)
            if (v & m.lb[j]) { v ^= m.eb[j]; im ^= m.ei[j]; }
        if (!v) continue;
        const unsigned l = lead_bit(v);
        int pos = m.n;
        while (pos > 0 && m.lb[pos - 1] < l) {
            m.eb[pos] = m.eb[pos - 1]; m.ei[pos] = m.ei[pos - 1]; m.lb[pos] = m.lb[pos - 1];
            --pos;
        }
        m.eb[pos] = v; m.ei[pos] = im; m.lb[pos] = l;
        ++m.n;
    }
    return m;
}

constexpr unsigned lmap_apply(const LMap& m, unsigned x) {
    unsigned r = x, acc = 0;
    for (int j = 0; j < m.n; ++j)
        if (r & m.lb[j]) { r ^= m.eb[j]; acc ^= m.ei[j]; }
    return acc;
}

constexpr Tab make_tab() {
    Tab tb{};
    unsigned col[12] = {}, row[12] = {};
    for (int w = 0; w < 12; ++w) { col[w] = 1u << (11 - w); row[w] = 1u << (11 - w); }
    for (int w = 0; w < 12; ++w) {           // layer-0 CNOTs (Rots in init)
        const int c = w, tg = (w + 1) % 12;
        col[c] ^= col[tg];
        row[tg] ^= row[c];
    }
    unsigned pm[15][4] = {}, pr[15][4] = {};
    {
        int pass = 0;
        for (int l = 1; l < 6; ++l) {
            for (int grp = 0; grp < 3; ++grp) {
                for (int i = 0; i < 4; ++i) {
                    const int w = grp * 4 + i;
                    pm[pass][i] = col[w];
                    pr[pass][i] = row[w];
                    tb.ggate[pass][i] = l * 12 + w;
                }
                ++pass;
            }
            const int r = l + 1;
            for (int w = 0; w < 12; ++w) {
                const int c = w, tg = (w + r) % 12;
                col[c] ^= col[tg];
                row[tg] ^= row[c];
            }
        }
        for (int w = 0; w < 12; ++w) tb.zrow[w] = row[w];
    }
    constexpr unsigned I_nb[8] = { 4u, 8u, 16u, 32u, 1024u, 2048u, 256u, 512u };
    constexpr unsigned I_m[4]  = { 1u, 2u, 64u, 128u };
    unsigned nbf[15][8] = {};
    for (int ps = 14; ps >= 0; --ps) {
        unsigned nbr[8] = {};
        nullspace12(pr[ps], 4, nbr);
        unsigned w_[8] = {};
        LMap lm{};
        bool have_lm = false;
        if (ps == 14) {
            for (int i = 0; i < 8; ++i) w_[i] = nbr[i];   // L_15 = identity
        } else {
            unsigned B[12] = {}, I[12] = {};
            for (int i = 0; i < 8; ++i) { B[i] = nbf[ps + 1][i]; I[i] = I_nb[i]; }
            for (int j = 0; j < 4; ++j) { B[8 + j] = pm[ps + 1][j]; I[8 + j] = I_m[j]; }
            lm = build_lmap(B, I);
            have_lm = true;
            for (int i = 0; i < 8; ++i) w_[i] = lmap_apply(lm, nbr[i]);
        }
        int pivrow[5] = { -1, -1, -1, -1, -1 };
        bool used[8] = {};
        for (int c = 0; c < 5; ++c) {
            int sel = -1;
            for (int i = 0; i < 8; ++i)
                if (!used[i] && ((w_[i] >> c) & 1u)) { sel = i; break; }
            if (sel < 0) continue;
            for (int i = 0; i < 8; ++i)
                if (i != sel && ((w_[i] >> c) & 1u)) { w_[i] ^= w_[sel]; nbr[i] ^= nbr[sel]; }
            used[sel] = true; pivrow[c] = sel;
        }
        unsigned fw[8] = {}, fn[8] = {};
        bool slot[8] = {}, ru[8] = {};
        for (int c = 0; c < 5; ++c)
            if (pivrow[c] >= 0) {
                fw[c] = w_[pivrow[c]]; fn[c] = nbr[pivrow[c]];
                ru[pivrow[c]] = true; slot[c] = true;
            }
        int fs = 0;
        for (int i = 0; i < 8; ++i) {
            if (ru[i]) continue;
            while (fs < 8 && slot[fs]) ++fs;
            fw[fs] = w_[i]; fn[fs] = nbr[i]; slot[fs] = true; ++fs;
        }
        for (int i = 0; i < 8; ++i) nbf[ps][i] = fn[i];
        const unsigned m0i = have_lm ? lmap_apply(lm, pm[ps][0]) : pm[ps][0];
        const unsigned m1i = have_lm ? lmap_apply(lm, pm[ps][1]) : pm[ps][1];
        const unsigned m2i = have_lm ? lmap_apply(lm, pm[ps][2]) : pm[ps][2];
        const unsigned m3i = have_lm ? lmap_apply(lm, pm[ps][3]) : pm[ps][3];
        for (int t = 0; t < 256; ++t) {
            unsigned qi = 0;
            if (t & 1)   qi ^= fw[0];
            if (t & 2)   qi ^= fw[1];
            if (t & 4)   qi ^= fw[2];
            if (t & 8)   qi ^= fw[3];
            if (t & 16)  qi ^= m1i;     // amp bit1 = l[4]
            if (t & 32)  qi ^= m2i;     // amp bit2 = l[5]
            if (t & 64)  qi ^= fw[6];   // wv bit0
            if (t & 128) qi ^= fw[7];   // wv bit1
            tb.qstore[ps][t] = (unsigned short)qi;
        }
        tb.smask[ps][0] = m0i;     // amp bit0 toggle
        tb.smask[ps][1] = m3i;     // amp bit3 toggle (row tile)
        tb.smask[ps][2] = fw[4];   // ct bit0
        tb.smask[ps][3] = fw[5];   // ct bit1
    }
    // init: writes into L_0
    {
        unsigned B[12] = {}, I[12] = {};
        for (int i = 0; i < 8; ++i) { B[i] = nbf[0][i]; I[i] = I_nb[i]; }
        for (int j = 0; j < 4; ++j) { B[8 + j] = pm[0][j]; I[8 + j] = I_m[j]; }
        const LMap lm0 = build_lmap(B, I);
        for (int t = 0; t < 256; ++t)
            tb.init_t[t] = (unsigned short)lmap_apply(lm0, (unsigned)t);
        for (int k = 0; k < 16; ++k)
            tb.initk[k] = (unsigned short)lmap_apply(lm0, (unsigned)(k << 8));
    }
    return tb;
}

__constant__ Tab GT = make_tab();

// layer-0 fold coefs [480 + w*8 + j]; fused pass operators (fp16, 32x32,
// interleaved-real rows/cols p = 2*amp + isIm), row-major 32/row.
__device__ float g_coef[576];
__device__ _Float16 g_umat[15 * 1024];

__device__ __forceinline__ void rot8(const float* __restrict__ wp, float* o) {
    const float phi = wp[0], th = wp[1], om = wp[2];
    const float hs = 0.5f * (phi + om), hd = 0.5f * (phi - om), ht = 0.5f * th;
    const float ctt = cosf(ht), stt = sinf(ht);
    const float cs = cosf(hs), ss = sinf(hs);
    const float cd = cosf(hd), sd = sinf(hd);
    o[0] = cs * ctt;  o[1] = -ss * ctt;   // u00
    o[2] = -cd * stt; o[3] = -sd * stt;   // u01
    o[4] = cd * stt;  o[5] = -sd * stt;   // u10
    o[6] = cs * ctt;  o[7] = ss * ctt;    // u11
}

// one block per pass: build the fused 32x32 real operator in fp16
__global__ void rot_coef_kernel(const float* __restrict__ weights) {
    __shared__ float ug[4][8];
    const int ps  = blockIdx.x;
    const int tid = threadIdx.x;
    if (ps == 0 && tid >= 32 && tid < 44) {      // layer-0 coefs (12 gates)
        const int w = tid - 32;
        float o[8];
        rot8(weights + w * 3, o);
        #pragma unroll
        for (int j = 0; j < 8; ++j) g_coef[480 + w * 8 + j] = o[j];
    }
    if (tid < 4) {
        float o[8];
        rot8(weights + GT.ggate[ps][tid] * 3, o);
        #pragma unroll
        for (int j = 0; j < 8; ++j) ug[tid][j] = o[j];
    }
    __syncthreads();
    _Float16* up = g_umat + ps * 1024;
    #pragma unroll
    for (int u = 0; u < 4; ++u) {
        const int pr = tid * 4 + u;          // (a', a) pair, 256 total
        const int ap = pr >> 4, a = pr & 15;
        float re = 1.0f, im = 0.0f;
        #pragma unroll
        for (int lev = 0; lev < 4; ++lev) {
            const int bi = (ap >> lev) & 1, bj = (a >> lev) & 1;
            const float cr = ug[lev][bi * 4 + bj * 2 + 0];
            const float ci = ug[lev][bi * 4 + bj * 2 + 1];
            const float nr = re * cr - im * ci;
            const float ni = re * ci + im * cr;
            re = nr; im = ni;
        }
        up[(2 * ap) * 32 + 2 * a]         = (_Float16)re;
        up[(2 * ap) * 32 + 2 * a + 1]     = (_Float16)(-im);
        up[(2 * ap + 1) * 32 + 2 * a]     = (_Float16)im;
        up[(2 * ap + 1) * 32 + 2 * a + 1] = (_Float16)re;
    }
}

__device__ __forceinline__ v2f cmulv(v2f A, v2f B) {
    return (v2f){ A.x * B.x - A.y * B.y, A.x * B.y + A.y * B.x };
}

// fp16 pack (RNE for init; RTZ single-instr in the hot loop) / unpack
__device__ __forceinline__ unsigned pk(v2f x) {
    h2 h = { (_Float16)x.x, (_Float16)x.y };
    return __builtin_bit_cast(unsigned, h);
}
__device__ __forceinline__ unsigned pkz(float x, float y) {
    return __builtin_bit_cast(unsigned, __builtin_amdgcn_cvt_pkrtz(x, y));
}
__device__ __forceinline__ v2f unpk(unsigned u) {
    h2 h = __builtin_bit_cast(h2, u);
    return (v2f){ (float)h.x, (float)h.y };
}

// ---------------------------------------------------------------------------
// One block (256 threads) per batch element. LDS = 2 x 16 KB ping-pong fp16
// state. 15 MFMA passes, ONE barrier each: read buf[ps&1], 8x mfma, pack,
// 16x b32 scatter into buf[(ps+1)&1] (next pass's layout).
// ---------------------------------------------------------------------------
__global__ __launch_bounds__(256) void qvl_fused(
    const float* __restrict__ v,        // (B, 512)
    const float* __restrict__ Wc,       // (12, 512)
    const float* __restrict__ bc,       // (12,)
    float* __restrict__ out)            // (B, 12)
{
    __shared__ alignas(16) unsigned st[2][4096];     // 32768 B LDS
    float* redf = reinterpret_cast<float*>(st[0]);   // overlay (48 floats)

    const int t    = threadIdx.x;
    const int lane = t & 63;
    const int wv   = t >> 6;
    const int b    = blockIdx.x;

    // ---- x_w = tanh(v[b] . Wc[w] + bc[w]) * pi (partials into overlay) -----
    {
        const float2 vv = reinterpret_cast<const float2*>(v + b * 512)[t];
        #pragma unroll
        for (int w = 0; w < 12; ++w) {
            const float2 ww = reinterpret_cast<const float2*>(Wc + w * 512)[t];
            float p = vv.x * ww.x + vv.y * ww.y;
            #pragma unroll
            for (int s = 1; s < 64; s <<= 1) p += __shfl_xor(p, s, 64);
            if (lane == 0) redf[w * 4 + wv] = p;
        }
    }
    __syncthreads();

    // ---- per-wave: lanes 0..11 fold RY(x_w) + layer-0 Rot into (aw, bw) ----
    float awx = 0.0f, awy = 0.0f, bwx = 0.0f, bwy = 0.0f;
    if (lane < 12) {
        const float x = tanhf(redf[lane * 4 + 0] + redf[lane * 4 + 1] +
                              redf[lane * 4 + 2] + redf[lane * 4 + 3] + bc[lane]) * PI_F;
        const float h = 0.5f * x;
        const float c = cosf(h), s = sinf(h);
        const float* c8 = g_coef + 480 + lane * 8;
        awx = c8[0] * c + c8[2] * s;  awy = c8[1] * c + c8[3] * s;
        bwx = c8[4] * c + c8[6] * s;  bwy = c8[5] * c + c8[7] * s;
    }
    __syncthreads();   // overlay reads done before init overwrites st[0]

    // ---- init: product state written into layout L_0, buffer 0 -------------
    {
        v2f hi = { 1.0f, 0.0f };
        #pragma unroll
        for (int j = 0; j < 8; ++j) {
            const int src = 11 - j;            // wire for p bit j
            const float ax = __shfl(awx, src, 64), ay = __shfl(awy, src, 64);
            const float bx = __shfl(bwx, src, 64), by = __shfl(bwy, src, 64);
            const int bit = (t >> j) & 1;
            hi = cmulv(hi, (v2f){ bit ? bx : ax, bit ? by : ay });
        }
        v2f A3 = { __shfl(awx, 3, 64), __shfl(awy, 3, 64) };
        v2f B3 = { __shfl(bwx, 3, 64), __shfl(bwy, 3, 64) };
        v2f A2 = { __shfl(awx, 2, 64), __shfl(awy, 2, 64) };
        v2f B2 = { __shfl(bwx, 2, 64), __shfl(bwy, 2, 64) };
        v2f A1 = { __shfl(awx, 1, 64), __shfl(awy, 1, 64) };
        v2f B1 = { __shfl(bwx, 1, 64), __shfl(bwy, 1, 64) };
        v2f A0 = { __shfl(awx, 0, 64), __shfl(awy, 0, 64) };
        v2f B0 = { __shfl(bwx, 0, 64), __shfl(bwy, 0, 64) };
        v2f fA[4], fB[4];
        #pragma unroll
        for (int m = 0; m < 4; ++m) {
            fA[m] = cmulv((m & 1) ? B3 : A3, (m & 2) ? B2 : A2);   // p bits 8,9
            fB[m] = cmulv((m & 1) ? B1 : A1, (m & 2) ? B0 : A0);   // p bits 10,11
        }
        const unsigned it = GT.init_t[t];
        #pragma unroll
        for (int k = 0; k < 16; ++k)
            st[0][it ^ GT.initk[k]] = pk(cmulv(hi, cmulv(fA[k & 3], fB[k >> 2])));
    }

    // ---- 15 MFMA passes, ping-pong buffers, one barrier each ----------------
    const f4 zacc = { 0.0f, 0.0f, 0.0f, 0.0f };
    #pragma unroll 1
    for (int ps = 0; ps < 15; ++ps) {
        unsigned base = GT.qstore[ps][t];
        const unsigned s0 = GT.smask[ps][0], s1 = GT.smask[ps][1];
        const unsigned s2 = GT.smask[ps][2], s3 = GT.smask[ps][3];
        const uint4* rb = reinterpret_cast<const uint4*>(st[ps & 1]);
        unsigned* wb = st[(ps + 1) & 1];
        __syncthreads();   // previous pass's stores visible

        // A: U rows (global, L2-resident); row = T*16 + (l&15), k-slice (l>>4)*8
        const _Float16* up = g_umat + ps * 1024 + (lane & 15) * 32 + (lane >> 4) * 8;
        const h8 Af0 = *reinterpret_cast<const h8*>(up);
        const h8 Af1 = *reinterpret_cast<const h8*>(up + 512);

        // B: state (4 coalesced b128); col = l&15, k-slice (l>>4)*8
        const uint4 bw0 = rb[t];
        const uint4 bw1 = rb[t + 256];
        const uint4 bw2 = rb[t + 512];
        const uint4 bw3 = rb[t + 768];
        const h8 Bf0 = __builtin_bit_cast(h8, bw0);
        const h8 Bf1 = __builtin_bit_cast(h8, bw1);
        const h8 Bf2 = __builtin_bit_cast(h8, bw2);
        const h8 Bf3 = __builtin_bit_cast(h8, bw3);

        asm volatile("" : "+v"(base));
        #define CTBLK(CT, BF)                                                   \
        {                                                                       \
            const f4 d0 = __builtin_amdgcn_mfma_f32_16x16x32_f16(Af0, BF, zacc, 0, 0, 0); \
            const f4 d1 = __builtin_amdgcn_mfma_f32_16x16x32_f16(Af1, BF, zacc, 0, 0, 0); \
            const unsigned a = base ^ ((CT & 1) ? s2 : 0u) ^ ((CT & 2) ? s3 : 0u); \
            wb[a]           = pkz(d0[0], d0[1]);                                \
            wb[a ^ s0]      = pkz(d0[2], d0[3]);                                \
            wb[a ^ s1]      = pkz(d1[0], d1[1]);                                \
            wb[a ^ s1 ^ s0] = pkz(d1[2], d1[3]);                                \
        }
        CTBLK(0, Bf0)
        CTBLK(1, Bf1)
        CTBLK(2, Bf2)
        CTBLK(3, Bf3)
        #undef CTBLK
    }
    __syncthreads();

    // ---- PauliZ expvals; final state in buf 1, identity layout -------------
    float p2[16];
    #pragma unroll
    for (int k = 0; k < 16; ++k) {
        const v2f aa = unpk(st[1][k * 256 + t]);
        p2[k] = aa.x * aa.x + aa.y * aa.y;
    }
    __syncthreads();   // all st reads done before overlay reuse
    #pragma unroll
    for (int w = 0; w < 12; ++w) {
        const unsigned zr = GT.zrow[w];
        const unsigned Aw = (unsigned)__popc((unsigned)t & zr) & 1u;
        const unsigned nm = (zr >> 8) & 0xFu;
        unsigned P = 0u;
        P ^= (nm & 1u) ? 0xAAAAu : 0u;
        P ^= (nm & 2u) ? 0xCCCCu : 0u;
        P ^= (nm & 4u) ? 0xF0F0u : 0u;
        P ^= (nm & 8u) ? 0xFF00u : 0u;
        P ^= Aw ? 0xFFFFu : 0u;
        float z = 0.0f;
        #pragma unroll
        for (int k = 0; k < 16; ++k)
            z += ((P >> k) & 1u) ? -p2[k] : p2[k];
        #pragma unroll
        for (int s = 1; s < 64; s <<= 1) z += __shfl_xor(z, s, 64);
        if (lane == 0) redf[w * 4 + wv] = z;
    }
    __syncthreads();
    if (t < 12)
        out[b * 12 + t] = redf[t * 4 + 0] + redf[t * 4 + 1] +
                          redf[t * 4 + 2] + redf[t * 4 + 3];
}

extern "C" void kernel_launch(void* const* d_in, const int* in_sizes, int n_in,
                              void* d_out, int out_size, void* d_ws, size_t ws_size,
                              hipStream_t stream) {
    (void)n_in; (void)out_size; (void)d_ws; (void)ws_size;
    const float* v   = (const float*)d_in[0];
    const float* Wc  = (const float*)d_in[1];
    const float* bc  = (const float*)d_in[2];
    const float* wts = (const float*)d_in[3];
    float* out = (float*)d_out;

    const int B = in_sizes[0] / 512;
    rot_coef_kernel<<<15, 64, 0, stream>>>(wts);
    qvl_fused<<<B, 256, 0, stream>>>(v, Wc, bc, out);
}

// Round 20
// 112.855 us; speedup vs baseline: 1.0620x; 1.0620x over previous
//
#include <hip/hip_runtime.h>
#include <math.h>

#define PI_F 3.14159265358979323846f

typedef float v2f __attribute__((ext_vector_type(2)));
typedef float f4 __attribute__((ext_vector_type(4)));
typedef _Float16 h2 __attribute__((ext_vector_type(2)));
typedef _Float16 h8 __attribute__((ext_vector_type(8)));

// ---------------------------------------------------------------------------
// R20 = R17 (single-buffer MFMA passes, 16 KB LDS, best measured) +
// pkrtz single-instruction packing (R19-verified absmax-safe) +
// A-fragment loads hoisted above the pass barrier (L2 latency hides under
// the barrier drain). All GF(2) layout machinery identical to R17.
// ---------------------------------------------------------------------------
struct Tab {
    int      ggate[15][4];           // gate index (layer*12 + wire)
    unsigned smask[15][4];           // {L(m0), L(m3), L(nb4)=ct0, L(nb5)=ct1}
    unsigned short qstore[15][256];  // store base (a0=0,a3=0,ct=0) per thread
    unsigned short init_t[256];      // L_0(t)
    unsigned short initk[16];        // L_0(k<<8)
    unsigned zrow[12];               // final measurement parity rows
};

constexpr int nullspace12(const unsigned* rows, int nr, unsigned* out) {
    unsigned R[8] = {};
    for (int i = 0; i < nr; ++i) R[i] = rows[i];
    int pivc[8] = {};
    int rank = 0;
    for (int c = 11; c >= 0; --c) {
        int sel = -1;
        for (int i = rank; i < nr; ++i) if ((R[i] >> c) & 1u) { sel = i; break; }
        if (sel < 0) continue;
        unsigned tmp = R[rank]; R[rank] = R[sel]; R[sel] = tmp;
        for (int i = 0; i < nr; ++i)
            if (i != rank && ((R[i] >> c) & 1u)) R[i] ^= R[rank];
        pivc[rank] = c; ++rank;
    }
    int nn = 0;
    for (int c = 0; c < 12; ++c) {
        bool isp = false;
        for (int i = 0; i < rank; ++i) if (pivc[i] == c) isp = true;
        if (isp) continue;
        unsigned v = 1u << c;
        for (int i = 0; i < rank; ++i)
            if ((R[i] >> c) & 1u) v |= 1u << pivc[i];
        out[nn++] = v;
    }
    return nn;
}

struct LMap {
    unsigned eb[12];
    unsigned ei[12];
    unsigned lb[12];
    int n;
};

constexpr unsigned lead_bit(unsigned v) {
    unsigned lb = 0;
    for (int c = 11; c >= 0; --c) if ((v >> c) & 1u) { lb = 1u << c; break; }
    return lb;
}

constexpr LMap build_lmap(const unsigned* B, const unsigned* I) {
    LMap m{};
    m.n = 0;
    for (int i = 0; i < 12; ++i) {
        unsigned v = B[i], im = I[i];
        for (int j = 0; j < m.n; ++j)
            if (v & m.lb[j]) { v ^= m.eb[j]; im ^= m.ei[j]; }
        if (!v) continue;
        const unsigned l = lead_bit(v);
        int pos = m.n;
        while (pos > 0 && m.lb[pos - 1] < l) {
            m.eb[pos] = m.eb[pos - 1]; m.ei[pos] = m.ei[pos - 1]; m.lb[pos] = m.lb[pos - 1];
            --pos;
        }
        m.eb[pos] = v; m.ei[pos] = im; m.lb[pos] = l;
        ++m.n;
    }
    return m;
}

constexpr unsigned lmap_apply(const LMap& m, unsigned x) {
    unsigned r = x, acc = 0;
    for (int j = 0; j < m.n; ++j)
        if (r & m.lb[j]) { r ^= m.eb[j]; acc ^= m.ei[j]; }
    return acc;
}

constexpr Tab make_tab() {
    Tab tb{};
    unsigned col[12] = {}, row[12] = {};
    for (int w = 0; w < 12; ++w) { col[w] = 1u << (11 - w); row[w] = 1u << (11 - w); }
    for (int w = 0; w < 12; ++w) {           // layer-0 CNOTs (Rots in init)
        const int c = w, tg = (w + 1) % 12;
        col[c] ^= col[tg];
        row[tg] ^= row[c];
    }
    unsigned pm[15][4] = {}, pr[15][4] = {};
    {
        int pass = 0;
        for (int l = 1; l < 6; ++l) {
            for (int grp = 0; grp < 3; ++grp) {
                for (int i = 0; i < 4; ++i) {
                    const int w = grp * 4 + i;
                    pm[pass][i] = col[w];
                    pr[pass][i] = row[w];
                    tb.ggate[pass][i] = l * 12 + w;
                }
                ++pass;
            }
            const int r = l + 1;
            for (int w = 0; w < 12; ++w) {
                const int c = w, tg = (w + r) % 12;
                col[c] ^= col[tg];
                row[tg] ^= row[c];
            }
        }
        for (int w = 0; w < 12; ++w) tb.zrow[w] = row[w];
    }
    // image bit assignment of layout L: nb slots and mask slots
    constexpr unsigned I_nb[8] = { 4u, 8u, 16u, 32u, 1024u, 2048u, 256u, 512u };
    constexpr unsigned I_m[4]  = { 1u, 2u, 64u, 128u };
    unsigned nbf[15][8] = {};
    for (int ps = 14; ps >= 0; --ps) {
        unsigned nbr[8] = {};
        nullspace12(pr[ps], 4, nbr);
        unsigned w_[8] = {};
        LMap lm{};
        bool have_lm = false;
        if (ps == 14) {
            for (int i = 0; i < 8; ++i) w_[i] = nbr[i];   // L_15 = identity
        } else {
            unsigned B[12] = {}, I[12] = {};
            for (int i = 0; i < 8; ++i) { B[i] = nbf[ps + 1][i]; I[i] = I_nb[i]; }
            for (int j = 0; j < 4; ++j) { B[8 + j] = pm[ps + 1][j]; I[8 + j] = I_m[j]; }
            lm = build_lmap(B, I);
            have_lm = true;
            for (int i = 0; i < 8; ++i) w_[i] = lmap_apply(lm, nbr[i]);
        }
        // simultaneous low-5 RREF on (w_, nbr): store-side bank coverage
        int pivrow[5] = { -1, -1, -1, -1, -1 };
        bool used[8] = {};
        for (int c = 0; c < 5; ++c) {
            int sel = -1;
            for (int i = 0; i < 8; ++i)
                if (!used[i] && ((w_[i] >> c) & 1u)) { sel = i; break; }
            if (sel < 0) continue;
            for (int i = 0; i < 8; ++i)
                if (i != sel && ((w_[i] >> c) & 1u)) { w_[i] ^= w_[sel]; nbr[i] ^= nbr[sel]; }
            used[sel] = true; pivrow[c] = sel;
        }
        unsigned fw[8] = {}, fn[8] = {};
        bool slot[8] = {}, ru[8] = {};
        for (int c = 0; c < 5; ++c)
            if (pivrow[c] >= 0) {
                fw[c] = w_[pivrow[c]]; fn[c] = nbr[pivrow[c]];
                ru[pivrow[c]] = true; slot[c] = true;
            }
        int fs = 0;
        for (int i = 0; i < 8; ++i) {
            if (ru[i]) continue;
            while (fs < 8 && slot[fs]) ++fs;
            fw[fs] = w_[i]; fn[fs] = nbr[i]; slot[fs] = true; ++fs;
        }
        for (int i = 0; i < 8; ++i) nbf[ps][i] = fn[i];
        const unsigned m0i = have_lm ? lmap_apply(lm, pm[ps][0]) : pm[ps][0];
        const unsigned m1i = have_lm ? lmap_apply(lm, pm[ps][1]) : pm[ps][1];
        const unsigned m2i = have_lm ? lmap_apply(lm, pm[ps][2]) : pm[ps][2];
        const unsigned m3i = have_lm ? lmap_apply(lm, pm[ps][3]) : pm[ps][3];
        for (int t = 0; t < 256; ++t) {
            unsigned qi = 0;
            if (t & 1)   qi ^= fw[0];
            if (t & 2)   qi ^= fw[1];
            if (t & 4)   qi ^= fw[2];
            if (t & 8)   qi ^= fw[3];
            if (t & 16)  qi ^= m1i;     // amp bit1 = l[4]
            if (t & 32)  qi ^= m2i;     // amp bit2 = l[5]
            if (t & 64)  qi ^= fw[6];   // wv bit0
            if (t & 128) qi ^= fw[7];   // wv bit1
            tb.qstore[ps][t] = (unsigned short)qi;
        }
        tb.smask[ps][0] = m0i;     // amp bit0 toggle
        tb.smask[ps][1] = m3i;     // amp bit3 toggle (row tile)
        tb.smask[ps][2] = fw[4];   // ct bit0
        tb.smask[ps][3] = fw[5];   // ct bit1
    }
    // init: writes into L_0
    {
        unsigned B[12] = {}, I[12] = {};
        for (int i = 0; i < 8; ++i) { B[i] = nbf[0][i]; I[i] = I_nb[i]; }
        for (int j = 0; j < 4; ++j) { B[8 + j] = pm[0][j]; I[8 + j] = I_m[j]; }
        const LMap lm0 = build_lmap(B, I);
        for (int t = 0; t < 256; ++t)
            tb.init_t[t] = (unsigned short)lmap_apply(lm0, (unsigned)t);
        for (int k = 0; k < 16; ++k)
            tb.initk[k] = (unsigned short)lmap_apply(lm0, (unsigned)(k << 8));
    }
    return tb;
}

__constant__ Tab GT = make_tab();

// layer-0 fold coefs [480 + w*8 + j]; fused pass operators (fp16, 32x32,
// interleaved-real rows/cols p = 2*amp + isIm), row-major 32/row.
__device__ float g_coef[576];
__device__ _Float16 g_umat[15 * 1024];

__device__ __forceinline__ void rot8(const float* __restrict__ wp, float* o) {
    const float phi = wp[0], th = wp[1], om = wp[2];
    const float hs = 0.5f * (phi + om), hd = 0.5f * (phi - om), ht = 0.5f * th;
    const float ctt = cosf(ht), stt = sinf(ht);
    const float cs = cosf(hs), ss = sinf(hs);
    const float cd = cosf(hd), sd = sinf(hd);
    o[0] = cs * ctt;  o[1] = -ss * ctt;   // u00
    o[2] = -cd * stt; o[3] = -sd * stt;   // u01
    o[4] = cd * stt;  o[5] = -sd * stt;   // u10
    o[6] = cs * ctt;  o[7] = ss * ctt;    // u11
}

// one block per pass: build the fused 32x32 real operator in fp16
__global__ void rot_coef_kernel(const float* __restrict__ weights) {
    __shared__ float ug[4][8];
    const int ps  = blockIdx.x;
    const int tid = threadIdx.x;
    if (ps == 0 && tid >= 32 && tid < 44) {      // layer-0 coefs (12 gates)
        const int w = tid - 32;
        float o[8];
        rot8(weights + w * 3, o);
        #pragma unroll
        for (int j = 0; j < 8; ++j) g_coef[480 + w * 8 + j] = o[j];
    }
    if (tid < 4) {
        float o[8];
        rot8(weights + GT.ggate[ps][tid] * 3, o);
        #pragma unroll
        for (int j = 0; j < 8; ++j) ug[tid][j] = o[j];
    }
    __syncthreads();
    _Float16* up = g_umat + ps * 1024;
    #pragma unroll
    for (int u = 0; u < 4; ++u) {
        const int pr = tid * 4 + u;          // (a', a) pair, 256 total
        const int ap = pr >> 4, a = pr & 15;
        float re = 1.0f, im = 0.0f;
        #pragma unroll
        for (int lev = 0; lev < 4; ++lev) {
            const int bi = (ap >> lev) & 1, bj = (a >> lev) & 1;
            const float cr = ug[lev][bi * 4 + bj * 2 + 0];
            const float ci = ug[lev][bi * 4 + bj * 2 + 1];
            const float nr = re * cr - im * ci;
            const float ni = re * ci + im * cr;
            re = nr; im = ni;
        }
        up[(2 * ap) * 32 + 2 * a]         = (_Float16)re;
        up[(2 * ap) * 32 + 2 * a + 1]     = (_Float16)(-im);
        up[(2 * ap + 1) * 32 + 2 * a]     = (_Float16)im;
        up[(2 * ap + 1) * 32 + 2 * a + 1] = (_Float16)re;
    }
}

__device__ __forceinline__ v2f cmulv(v2f A, v2f B) {
    return (v2f){ A.x * B.x - A.y * B.y, A.x * B.y + A.y * B.x };
}

// fp16 pack (RNE for init; single-instr RTZ in the hot loop) / unpack
__device__ __forceinline__ unsigned pk(v2f x) {
    h2 h = { (_Float16)x.x, (_Float16)x.y };
    return __builtin_bit_cast(unsigned, h);
}
__device__ __forceinline__ unsigned pkz(float x, float y) {
    return __builtin_bit_cast(unsigned, __builtin_amdgcn_cvt_pkrtz(x, y));
}
__device__ __forceinline__ v2f unpk(unsigned u) {
    h2 h = __builtin_bit_cast(h2, u);
    return (v2f){ (float)h.x, (float)h.y };
}

// ---------------------------------------------------------------------------
// One block (256 threads) per batch element. LDS = 16 KB fp16 state.
// 15 MFMA passes: A loads issued BEFORE the barrier (latency hides under the
// drain), 4x b128 LDS loads (B), 8x mfma_f32_16x16x32_f16, pkrtz pack,
// 16x b32 scatter into the next pass's layout.
// ---------------------------------------------------------------------------
__global__ __launch_bounds__(256) void qvl_fused(
    const float* __restrict__ v,        // (B, 512)
    const float* __restrict__ Wc,       // (12, 512)
    const float* __restrict__ bc,       // (12,)
    float* __restrict__ out)            // (B, 12)
{
    __shared__ alignas(16) unsigned st[4096];     // 16384 B LDS
    float* redf = reinterpret_cast<float*>(st);   // overlay (48 floats)
    uint4* st4 = reinterpret_cast<uint4*>(st);

    const int t    = threadIdx.x;
    const int lane = t & 63;
    const int wv   = t >> 6;
    const int b    = blockIdx.x;

    // ---- x_w = tanh(v[b] . Wc[w] + bc[w]) * pi (partials into overlay) -----
    {
        const float2 vv = reinterpret_cast<const float2*>(v + b * 512)[t];
        #pragma unroll
        for (int w = 0; w < 12; ++w) {
            const float2 ww = reinterpret_cast<const float2*>(Wc + w * 512)[t];
            float p = vv.x * ww.x + vv.y * ww.y;
            #pragma unroll
            for (int s = 1; s < 64; s <<= 1) p += __shfl_xor(p, s, 64);
            if (lane == 0) redf[w * 4 + wv] = p;
        }
    }
    __syncthreads();

    // ---- per-wave: lanes 0..11 fold RY(x_w) + layer-0 Rot into (aw, bw) ----
    float awx = 0.0f, awy = 0.0f, bwx = 0.0f, bwy = 0.0f;
    if (lane < 12) {
        const float x = tanhf(redf[lane * 4 + 0] + redf[lane * 4 + 1] +
                              redf[lane * 4 + 2] + redf[lane * 4 + 3] + bc[lane]) * PI_F;
        const float h = 0.5f * x;
        const float c = cosf(h), s = sinf(h);
        const float* c8 = g_coef + 480 + lane * 8;
        awx = c8[0] * c + c8[2] * s;  awy = c8[1] * c + c8[3] * s;
        bwx = c8[4] * c + c8[6] * s;  bwy = c8[5] * c + c8[7] * s;
    }
    __syncthreads();   // overlay reads done before init overwrites st

    // ---- init: product state written into layout L_0 (fp16 packed) ---------
    {
        v2f hi = { 1.0f, 0.0f };
        #pragma unroll
        for (int j = 0; j < 8; ++j) {
            const int src = 11 - j;            // wire for p bit j
            const float ax = __shfl(awx, src, 64), ay = __shfl(awy, src, 64);
            const float bx = __shfl(bwx, src, 64), by = __shfl(bwy, src, 64);
            const int bit = (t >> j) & 1;
            hi = cmulv(hi, (v2f){ bit ? bx : ax, bit ? by : ay });
        }
        v2f A3 = { __shfl(awx, 3, 64), __shfl(awy, 3, 64) };
        v2f B3 = { __shfl(bwx, 3, 64), __shfl(bwy, 3, 64) };
        v2f A2 = { __shfl(awx, 2, 64), __shfl(awy, 2, 64) };
        v2f B2 = { __shfl(bwx, 2, 64), __shfl(bwy, 2, 64) };
        v2f A1 = { __shfl(awx, 1, 64), __shfl(awy, 1, 64) };
        v2f B1 = { __shfl(bwx, 1, 64), __shfl(bwy, 1, 64) };
        v2f A0 = { __shfl(awx, 0, 64), __shfl(awy, 0, 64) };
        v2f B0 = { __shfl(bwx, 0, 64), __shfl(bwy, 0, 64) };
        v2f fA[4], fB[4];
        #pragma unroll
        for (int m = 0; m < 4; ++m) {
            fA[m] = cmulv((m & 1) ? B3 : A3, (m & 2) ? B2 : A2);   // p bits 8,9
            fB[m] = cmulv((m & 1) ? B1 : A1, (m & 2) ? B0 : A0);   // p bits 10,11
        }
        const unsigned it = GT.init_t[t];
        #pragma unroll
        for (int k = 0; k < 16; ++k)
            st[it ^ GT.initk[k]] = pk(cmulv(hi, cmulv(fA[k & 3], fB[k >> 2])));
    }

    // ---- 15 MFMA passes (layers 1..5, 4 gates each) --------------------------
    const f4 zacc = { 0.0f, 0.0f, 0.0f, 0.0f };
    #pragma unroll 1
    for (int ps = 0; ps < 15; ++ps) {
        // A: U rows (global, L2-resident) — issued BEFORE the barrier so the
        // ~200cy L2 latency hides under the barrier drain (no LDS dependency)
        const _Float16* up = g_umat + ps * 1024 + (lane & 15) * 32 + (lane >> 4) * 8;
        const h8 Af0 = *reinterpret_cast<const h8*>(up);
        const h8 Af1 = *reinterpret_cast<const h8*>(up + 512);
        unsigned base = GT.qstore[ps][t];
        const unsigned s0 = GT.smask[ps][0], s1 = GT.smask[ps][1];
        const unsigned s2 = GT.smask[ps][2], s3 = GT.smask[ps][3];

        __syncthreads();   // previous stores complete

        // B: state (4 coalesced b128); col = l&15, k-slice (l>>4)*8
        const uint4 bw0 = st4[t];
        const uint4 bw1 = st4[t + 256];
        const uint4 bw2 = st4[t + 512];
        const uint4 bw3 = st4[t + 768];
        const h8 Bf0 = __builtin_bit_cast(h8, bw0);
        const h8 Bf1 = __builtin_bit_cast(h8, bw1);
        const h8 Bf2 = __builtin_bit_cast(h8, bw2);
        const h8 Bf3 = __builtin_bit_cast(h8, bw3);

        __syncthreads();   // all loads complete before scatter stores

        asm volatile("" : "+v"(base));
        #define CTBLK(CT, BF)                                                   \
        {                                                                       \
            const f4 d0 = __builtin_amdgcn_mfma_f32_16x16x32_f16(Af0, BF, zacc, 0, 0, 0); \
            const f4 d1 = __builtin_amdgcn_mfma_f32_16x16x32_f16(Af1, BF, zacc, 0, 0, 0); \
            const unsigned a = base ^ ((CT & 1) ? s2 : 0u) ^ ((CT & 2) ? s3 : 0u); \
            st[a]           = pkz(d0[0], d0[1]);                                \
            st[a ^ s0]      = pkz(d0[2], d0[3]);                                \
            st[a ^ s1]      = pkz(d1[0], d1[1]);                                \
            st[a ^ s1 ^ s0] = pkz(d1[2], d1[3]);                                \
        }
        CTBLK(0, Bf0)
        CTBLK(1, Bf1)
        CTBLK(2, Bf2)
        CTBLK(3, Bf3)
        #undef CTBLK
    }
    __syncthreads();

    // ---- PauliZ expvals; final layout is identity: word addr = p -----------
    float p2[16];
    #pragma unroll
    for (int k = 0; k < 16; ++k) {
        const v2f aa = unpk(st[k * 256 + t]);
        p2[k] = aa.x * aa.x + aa.y * aa.y;
    }
    __syncthreads();   // all st reads done before overlay reuse
    #pragma unroll
    for (int w = 0; w < 12; ++w) {
        const unsigned zr = GT.zrow[w];
        const unsigned Aw = (unsigned)__popc((unsigned)t & zr) & 1u;
        const unsigned nm = (zr >> 8) & 0xFu;
        unsigned P = 0u;
        P ^= (nm & 1u) ? 0xAAAAu : 0u;
        P ^= (nm & 2u) ? 0xCCCCu : 0u;
        P ^= (nm & 4u) ? 0xF0F0u : 0u;
        P ^= (nm & 8u) ? 0xFF00u : 0u;
        P ^= Aw ? 0xFFFFu : 0u;
        float z = 0.0f;
        #pragma unroll
        for (int k = 0; k < 16; ++k)
            z += ((P >> k) & 1u) ? -p2[k] : p2[k];
        #pragma unroll
        for (int s = 1; s < 64; s <<= 1) z += __shfl_xor(z, s, 64);
        if (lane == 0) redf[w * 4 + wv] = z;
    }
    __syncthreads();
    if (t < 12)
        out[b * 12 + t] = redf[t * 4 + 0] + redf[t * 4 + 1] +
                          redf[t * 4 + 2] + redf[t * 4 + 3];
}

extern "C" void kernel_launch(void* const* d_in, const int* in_sizes, int n_in,
                              void* d_out, int out_size, void* d_ws, size_t ws_size,
                              hipStream_t stream) {
    (void)n_in; (void)out_size; (void)d_ws; (void)ws_size;
    const float* v   = (const float*)d_in[0];
    const float* Wc  = (const float*)d_in[1];
    const float* bc  = (const float*)d_in[2];
    const float* wts = (const float*)d_in[3];
    float* out = (float*)d_out;

    const int B = in_sizes[0] / 512;
    rot_coef_kernel<<<15, 64, 0, stream>>>(wts);
    qvl_fused<<<B, 256, 0, stream>>>(v, Wc, bc, out);
}